// Round 1
// baseline (386.976 us; speedup 1.0000x reference)
//
#include <hip/hip_runtime.h>
#include <hip/hip_bf16.h>
#include <string.h>

#define BB 128
#define UU 200
#define DD 512
#define NP 256

typedef __attribute__((ext_vector_type(8))) short short8;
typedef __attribute__((ext_vector_type(4))) float f32x4;

__device__ __forceinline__ unsigned pack_bf16_2(float a, float b) {
    __hip_bfloat162 h = __float22bfloat162_rn(make_float2(a, b));
    unsigned u; memcpy(&u, &h, 4); return u;
}

__device__ __forceinline__ unsigned short f2bf(float x) {
    union { float f; unsigned u; } v; v.f = x;
    unsigned r = v.u + 0x7FFFu + ((v.u >> 16) & 1u);
    return (unsigned short)(r >> 16);
}

// ---- build plain bf16 tables Kbr[n][j], Kbi[n][j] (n padded to 256 with zeros).
// Also pre-zeroes out[] (25600 < 131072, same stream => done before gemm atomics).
__global__ void kb2_build_kernel(const float* __restrict__ Kt,
                                 unsigned short* __restrict__ Kbr,
                                 unsigned short* __restrict__ Kbi,
                                 float* __restrict__ out) {
    int idx = blockIdx.x * 256 + threadIdx.x;    // 0..131071 (256 n x 512 j)
    int n = idx >> 9, j = idx & 511;
    unsigned short r = 0, im = 0;
    if (n < UU) {
        float2 s = ((const float2*)Kt)[(size_t)n * DD + j];
        r = f2bf(s.x); im = f2bf(s.y);
    }
    Kbr[idx] = r;
    Kbi[idx] = im;
    if (idx < BB * UU) out[idx] = 0.0f;
}

__global__ void zero_out_kernel(float* __restrict__ out) {
    int i = blockIdx.x * 256 + threadIdx.x;
    if (i < BB * UU) out[i] = 0.0f;
}

// ---- quadratic-form GEMM:
//   Mr[i,n] = sum_j Ar[b,i,j]*kr[n,j] - Ai[b,i,j]*ki[n,j]
//   Mi[i,n] = sum_j Ar[b,i,j]*ki[n,j] + Ai[b,i,j]*kr[n,j]
//   out[b,n] += sum_i kr[n,i]*Mr[i,n] - ki[n,i]*Mi[i,n]   (i-contraction in-block)
// Block = (b, 64-row i-chunk). 512 threads = 8 waves; wave w owns n-slice [32w,32w+32).
// 2 blocks/CU co-resident (32KB LDS, <=128 regs) so barriers overlap across blocks.
__global__ __launch_bounds__(512, 4) void qf_gemm_kernel(
    const float* __restrict__ Ar, const float* __restrict__ Ai,
    const float* __restrict__ Kt,
    const unsigned short* __restrict__ Kbr, const unsigned short* __restrict__ Kbi,
    float* __restrict__ out)
{
    __shared__ short sA[2][2][64 * 64];   // [dbuf][Ar/Ai][row*64+j], XOR-swizzled, 32 KB

    const int tid  = threadIdx.x;
    const int bx   = blockIdx.x;          // 0..1023
    const int b    = bx >> 3;
    const int i0   = (bx & 7) * 64;

    const int w    = tid >> 6;            // 0..7
    const int lane = tid & 63;
    const int rrow = lane & 15;
    const int quad = lane >> 4;
    const int xr   = rrow & 7;
    const int nn0  = w * 32 + rrow;       // n-tile 0 column
    const int nn1  = nn0 + 16;            // n-tile 1 column

    // staging: thread loads 2 rows x 4 floats per tensor per substage (64x64 chunk)
    const int g  = tid & 15;              // j-group (g*4 floats)
    const int r0 = tid >> 4;              // 0..31 -> rows r0, r0+32
    const float* ArB = Ar + ((size_t)b * DD + i0) * DD;
    const float* AiB = Ai + ((size_t)b * DD + i0) * DD;
    unsigned aoff[2];
    int waddr[2];
#pragma unroll
    for (int l = 0; l < 2; ++l) {
        int row = r0 + 32 * l;
        aoff[l]  = (unsigned)row * DD + (unsigned)g * 4;
        waddr[l] = row * 64 + (((g >> 1) ^ (row & 7)) * 8) + (g & 1) * 4;
    }

    // LDS read bases (in shorts): granule kk*4+quad, XOR-swizzled by rrow&7
    const int rb0 = rrow * 64 + ((quad ^ xr)) * 8;        // kk=0
    const int rb1 = rrow * 64 + ((quad ^ xr) ^ 4) * 8;    // kk=1: (4+quad)^xr = (quad^xr)^4

    f32x4 accr[4][2], acci[4][2];
#pragma unroll
    for (int m = 0; m < 4; ++m)
#pragma unroll
        for (int nt = 0; nt < 2; ++nt) { accr[m][nt] = (f32x4)(0.f); acci[m][nt] = (f32x4)(0.f); }

    // prologue prefetch (substage 0)
    f32x4 pf[4];
    pf[0] = *(const f32x4*)(ArB + aoff[0]);
    pf[1] = *(const f32x4*)(ArB + aoff[1]);
    pf[2] = *(const f32x4*)(AiB + aoff[0]);
    pf[3] = *(const f32x4*)(AiB + aoff[1]);

#pragma unroll 2
    for (int ss = 0; ss < 8; ++ss) {
        short* bufR = &sA[ss & 1][0][0];
        short* bufI = &sA[ss & 1][1][0];

        // convert prefetched fp32 -> bf16 LDS (swizzled)
#pragma unroll
        for (int l = 0; l < 2; ++l) {
            uint2 u, v;
            u.x = pack_bf16_2(pf[l][0], pf[l][1]);
            u.y = pack_bf16_2(pf[l][2], pf[l][3]);
            v.x = pack_bf16_2(pf[2 + l][0], pf[2 + l][1]);
            v.y = pack_bf16_2(pf[2 + l][2], pf[2 + l][3]);
            *(uint2*)&bufR[waddr[l]] = u;
            *(uint2*)&bufI[waddr[l]] = v;
        }
        __syncthreads();   // single barrier per substage (dbuf makes it sufficient)

        // issue next substage's global loads (fly during MFMA below)
        if (ss < 7) {
            const unsigned jn = (unsigned)(ss + 1) * 64;
            pf[0] = *(const f32x4*)(ArB + aoff[0] + jn);
            pf[1] = *(const f32x4*)(ArB + aoff[1] + jn);
            pf[2] = *(const f32x4*)(AiB + aoff[0] + jn);
            pf[3] = *(const f32x4*)(AiB + aoff[1] + jn);
        }

        const int jbase = ss * 64;
#pragma unroll
        for (int kk = 0; kk < 2; ++kk) {
            const int j = jbase + kk * 32 + quad * 8;
            short8 bkr0 = *(const short8*)(Kbr + (size_t)nn0 * 512 + j);
            short8 bkr1 = *(const short8*)(Kbr + (size_t)nn1 * 512 + j);
            short8 bki0 = *(const short8*)(Kbi + (size_t)nn0 * 512 + j);
            short8 bki1 = *(const short8*)(Kbi + (size_t)nn1 * 512 + j);
            const int rb = kk ? rb1 : rb0;

            short8 afR[4];
#pragma unroll
            for (int m = 0; m < 4; ++m)
                afR[m] = *(const short8*)&bufR[rb + m * 1024];
#pragma unroll
            for (int m = 0; m < 4; ++m) {
                accr[m][0] = __builtin_amdgcn_mfma_f32_16x16x32_bf16(afR[m], bkr0, accr[m][0], 0, 0, 0);
                accr[m][1] = __builtin_amdgcn_mfma_f32_16x16x32_bf16(afR[m], bkr1, accr[m][1], 0, 0, 0);
                acci[m][0] = __builtin_amdgcn_mfma_f32_16x16x32_bf16(afR[m], bki0, acci[m][0], 0, 0, 0);
                acci[m][1] = __builtin_amdgcn_mfma_f32_16x16x32_bf16(afR[m], bki1, acci[m][1], 0, 0, 0);
            }

            // negate ki in place (bf16 sign flip on packed pairs)
            union { short8 v; unsigned u[4]; } t0, t1;
            t0.v = bki0; t1.v = bki1;
#pragma unroll
            for (int e = 0; e < 4; ++e) { t0.u[e] ^= 0x80008000u; t1.u[e] ^= 0x80008000u; }

            short8 afI[4];
#pragma unroll
            for (int m = 0; m < 4; ++m)
                afI[m] = *(const short8*)&bufI[rb + m * 1024];
#pragma unroll
            for (int m = 0; m < 4; ++m) {
                accr[m][0] = __builtin_amdgcn_mfma_f32_16x16x32_bf16(afI[m], t0.v, accr[m][0], 0, 0, 0);
                accr[m][1] = __builtin_amdgcn_mfma_f32_16x16x32_bf16(afI[m], t1.v, accr[m][1], 0, 0, 0);
                acci[m][0] = __builtin_amdgcn_mfma_f32_16x16x32_bf16(afI[m], bkr0, acci[m][0], 0, 0, 0);
                acci[m][1] = __builtin_amdgcn_mfma_f32_16x16x32_bf16(afI[m], bkr1, acci[m][1], 0, 0, 0);
            }
        }
    }

    // ---- epilogue: i-contraction with f32 kernel, cross-quad reduce, one atomic per n
    // acc element (m,nt,r) sits at (i = i0 + m*16 + quad*4 + r, n = w*32 + nt*16 + rrow)
    float* outB = out + (size_t)b * UU;
#pragma unroll
    for (int nt = 0; nt < 2; ++nt) {
        const int n = w * 32 + nt * 16 + rrow;
        float s = 0.f;
        if (n < UU) {
            const float* kp = Kt + ((size_t)n * DD + i0 + quad * 4) * 2;  // (kr,ki) pairs
#pragma unroll
            for (int m = 0; m < 4; ++m) {
                f32x4 k01 = *(const f32x4*)(kp + m * 32);        // i+0,i+1: kr,ki,kr,ki
                f32x4 k23 = *(const f32x4*)(kp + m * 32 + 4);    // i+2,i+3
                s += accr[m][nt][0] * k01[0] - acci[m][nt][0] * k01[1];
                s += accr[m][nt][1] * k01[2] - acci[m][nt][1] * k01[3];
                s += accr[m][nt][2] * k23[0] - acci[m][nt][2] * k23[1];
                s += accr[m][nt][3] * k23[2] - acci[m][nt][3] * k23[3];
            }
        }
        s += __shfl_xor(s, 16, 64);
        s += __shfl_xor(s, 32, 64);
        if (quad == 0 && n < UU)
            atomicAdd(&outB[n], s);   // 8 i-chunk blocks per (b,n): trivial contention
    }
}

// ---- fallback (ws too small): self-contained atomic kernel, f32 Kt synthesis in LDS
#define ASTR 40
#define WSTR 40
__global__ __launch_bounds__(512, 4) void cm_gemm_fb_kernel(
    const float* __restrict__ Ar, const float* __restrict__ Ai,
    const float* __restrict__ Kt, float* __restrict__ dst)
{
    __shared__ short sAr[BB * ASTR];
    __shared__ short sAi[BB * ASTR];
    __shared__ short sWr[NP * WSTR];
    __shared__ short sWi[NP * WSTR];
    const int tid = threadIdx.x, irow = blockIdx.x;
    const int w = tid >> 6, lane = tid & 63;
    const int mw = (w & 1) * 64, nw = (w >> 1) * 64;
    const int rrow = lane & 15, quad = lane >> 4;
    const int nW = tid >> 1, jh = (tid & 1) * 16;
    float krI = 0.f, kiI = 0.f;
    if (nW < UU) { float2 s = ((const float2*)Kt)[(size_t)nW * DD + irow]; krI = s.x; kiI = s.y; }
    const int brow0 = tid >> 3, grp = tid & 7;
    const size_t aoff0 = (size_t)brow0 * DD * DD + (size_t)irow * DD + (size_t)grp * 4;
    const size_t aoff1 = aoff0 + (size_t)64 * DD * DD;
    f32x4 acc[4][4];
#pragma unroll
    for (int a = 0; a < 4; ++a)
#pragma unroll
        for (int c = 0; c < 4; ++c) acc[a][c] = (f32x4)(0.f);
    for (int jw = 0; jw < DD; jw += 32) {
        f32x4 vr0 = *(const f32x4*)(Ar + aoff0 + jw);
        f32x4 vr1 = *(const f32x4*)(Ar + aoff1 + jw);
        f32x4 vi0 = *(const f32x4*)(Ai + aoff0 + jw);
        f32x4 vi1 = *(const f32x4*)(Ai + aoff1 + jw);
        union { unsigned short s[4]; uint2 u; } t0, t1, t2, t3;
#pragma unroll
        for (int q = 0; q < 4; ++q) {
            t0.s[q] = f2bf(vr0[q]); t1.s[q] = f2bf(vr1[q]);
            t2.s[q] = f2bf(vi0[q]); t3.s[q] = f2bf(vi1[q]);
        }
        *(uint2*)&sAr[ brow0       * ASTR + grp * 4] = t0.u;
        *(uint2*)&sAr[(brow0 + 64) * ASTR + grp * 4] = t1.u;
        *(uint2*)&sAi[ brow0       * ASTR + grp * 4] = t2.u;
        *(uint2*)&sAi[(brow0 + 64) * ASTR + grp * 4] = t3.u;
        if (nW < UU) {
            const f32x4* kv = (const f32x4*)(Kt + (size_t)nW * DD * 2 + (size_t)(jw + jh) * 2);
#pragma unroll
            for (int q = 0; q < 8; ++q) {
                f32x4 v = kv[q];
                float wr0 = krI * v[0] - kiI * v[1], wi0 = -(krI * v[1] + kiI * v[0]);
                float wr1 = krI * v[2] - kiI * v[3], wi1 = -(krI * v[3] + kiI * v[2]);
                *(unsigned*)&sWr[nW * WSTR + jh + 2 * q] = (unsigned)f2bf(wr0) | ((unsigned)f2bf(wr1) << 16);
                *(unsigned*)&sWi[nW * WSTR + jh + 2 * q] = (unsigned)f2bf(wi0) | ((unsigned)f2bf(wi1) << 16);
            }
        } else {
#pragma unroll
            for (int q = 0; q < 8; ++q) {
                *(unsigned*)&sWr[nW * WSTR + jh + 2 * q] = 0u;
                *(unsigned*)&sWi[nW * WSTR + jh + 2 * q] = 0u;
            }
        }
        __syncthreads();
#pragma unroll
        for (int ph = 0; ph < 2; ++ph) {
            const short* sA = ph ? sAi : sAr;
            const short* sW = ph ? sWi : sWr;
            short8 af[4], bf[4];
#pragma unroll
            for (int t = 0; t < 4; ++t) {
                af[t] = *(const short8*)&sA[(mw + t * 16 + rrow) * ASTR + quad * 8];
                bf[t] = *(const short8*)&sW[(nw + t * 16 + rrow) * WSTR + quad * 8];
            }
#pragma unroll
            for (int ti = 0; ti < 4; ++ti)
#pragma unroll
                for (int tj = 0; tj < 4; ++tj)
                    acc[ti][tj] = __builtin_amdgcn_mfma_f32_16x16x32_bf16(af[ti], bf[tj], acc[ti][tj], 0, 0, 0);
        }
        __syncthreads();
    }
#pragma unroll
    for (int ti = 0; ti < 4; ++ti) {
        int m = mw + ti * 16 + quad * 4;
#pragma unroll
        for (int tj = 0; tj < 4; ++tj) {
            int n = nw + tj * 16 + rrow;
            if (n < UU)
#pragma unroll
                for (int r = 0; r < 4; ++r)
                    atomicAdd(&dst[(size_t)(m + r) * UU + n], acc[ti][tj][r]);
        }
    }
}

extern "C" void kernel_launch(void* const* d_in, const int* in_sizes, int n_in,
                              void* d_out, int out_size, void* d_ws, size_t ws_size,
                              hipStream_t stream) {
    const float* Ar = (const float*)d_in[0];
    const float* Ai = (const float*)d_in[1];
    const float* Kt = (const float*)d_in[2];
    float* out = (float*)d_out;

    const size_t kb_need = (size_t)2 * NP * DD * sizeof(unsigned short);  // 512 KB

    if (ws_size >= kb_need) {
        unsigned short* Kbr = (unsigned short*)d_ws;
        unsigned short* Kbi = Kbr + (size_t)NP * DD;
        hipLaunchKernelGGL(kb2_build_kernel, dim3(512), dim3(256), 0, stream, Kt, Kbr, Kbi, out);
        hipLaunchKernelGGL(qf_gemm_kernel, dim3(1024), dim3(512), 0, stream,
                           Ar, Ai, Kt, Kbr, Kbi, out);
    } else {
        hipLaunchKernelGGL(zero_out_kernel, dim3(100), dim3(256), 0, stream, out);
        hipLaunchKernelGGL(cm_gemm_fb_kernel, dim3(DD), dim3(512), 0, stream, Ar, Ai, Kt, out);
    }
}

// Round 2
// 355.858 us; speedup vs baseline: 1.0874x; 1.0874x over previous
//
#include <hip/hip_runtime.h>
#include <hip/hip_bf16.h>
#include <string.h>

#define BB 128
#define UU 200
#define DD 512
#define NP 256

typedef __attribute__((ext_vector_type(8))) short short8;
typedef __attribute__((ext_vector_type(4))) float f32x4;

__device__ __forceinline__ unsigned pack_bf16_2(float a, float b) {
    __hip_bfloat162 h = __float22bfloat162_rn(make_float2(a, b));
    unsigned u; memcpy(&u, &h, 4); return u;
}

__device__ __forceinline__ unsigned short f2bf(float x) {
    union { float f; unsigned u; } v; v.f = x;
    unsigned r = v.u + 0x7FFFu + ((v.u >> 16) & 1u);
    return (unsigned short)(r >> 16);
}

// ---- build plain bf16 tables Kbr[n][j], Kbi[n][j] (n padded to 256 with zeros).
// Also pre-zeroes out[] (25600 < 131072, same stream => done before gemm atomics).
__global__ void kb2_build_kernel(const float* __restrict__ Kt,
                                 unsigned short* __restrict__ Kbr,
                                 unsigned short* __restrict__ Kbi,
                                 float* __restrict__ out) {
    int idx = blockIdx.x * 256 + threadIdx.x;    // 0..131071 (256 n x 512 j)
    int n = idx >> 9, j = idx & 511;
    unsigned short r = 0, im = 0;
    if (n < UU) {
        float2 s = ((const float2*)Kt)[(size_t)n * DD + j];
        r = f2bf(s.x); im = f2bf(s.y);
    }
    Kbr[idx] = r;
    Kbi[idx] = im;
    if (idx < BB * UU) out[idx] = 0.0f;
}

__global__ void zero_out_kernel(float* __restrict__ out) {
    int i = blockIdx.x * 256 + threadIdx.x;
    if (i < BB * UU) out[i] = 0.0f;
}

// ---- quadratic-form GEMM:
//   Mr[i,n] = sum_j Ar[b,i,j]*kr[n,j] - Ai[b,i,j]*ki[n,j]
//   Mi[i,n] = sum_j Ar[b,i,j]*ki[n,j] + Ai[b,i,j]*kr[n,j]
//   out[b,n] += sum_i kr[n,i]*Mr[i,n] - ki[n,i]*Mi[i,n]   (i-contraction in-block)
// Block = (b, 32-row i-chunk): grid 2048. 512 threads = 8 waves; wave w owns
// n-slice [32w, 32w+32). M=32 keeps acc at 32 regs/thread -> ~90 regs total,
// no scratch spill (round-1's 148MB WRITE_SIZE killer) at launch_bounds(512,4).
// 16KB LDS -> 2 blocks/CU co-resident so barriers overlap across blocks.
__global__ __launch_bounds__(512, 4) void qf_gemm_kernel(
    const float* __restrict__ Ar, const float* __restrict__ Ai,
    const float* __restrict__ Kt,
    const unsigned short* __restrict__ Kbr, const unsigned short* __restrict__ Kbi,
    float* __restrict__ out)
{
    __shared__ short sA[2][2][32 * 64];   // [dbuf][Ar/Ai][row*64+j], XOR-swizzled, 16 KB

    const int tid  = threadIdx.x;
    const int bx   = blockIdx.x;          // 0..2047
    const int b    = bx >> 4;
    const int i0   = (bx & 15) * 32;

    const int w    = tid >> 6;            // 0..7
    const int lane = tid & 63;
    const int rrow = lane & 15;
    const int quad = lane >> 4;
    const int xr   = rrow & 7;
    const int nn0  = w * 32 + rrow;       // n-tile 0 column
    const int nn1  = nn0 + 16;            // n-tile 1 column

    // staging: thread loads 1 granule (4 floats) per tensor per substage (32x64 chunk)
    const int g  = tid & 15;              // j-group (g*4 floats)
    const int r0 = tid >> 4;              // row 0..31
    const float* ArB = Ar + ((size_t)b * DD + i0) * DD;
    const float* AiB = Ai + ((size_t)b * DD + i0) * DD;
    const unsigned aoff  = (unsigned)r0 * DD + (unsigned)g * 4;
    const int      waddr = r0 * 64 + (((g >> 1) ^ (r0 & 7)) * 8) + (g & 1) * 4;

    // LDS read bases (in shorts): granule kk*4+quad, XOR-swizzled by rrow&7
    const int rb0 = rrow * 64 + ((quad ^ xr)) * 8;        // kk=0
    const int rb1 = rrow * 64 + ((quad ^ xr) ^ 4) * 8;    // kk=1

    f32x4 accr[2][2], acci[2][2];
#pragma unroll
    for (int m = 0; m < 2; ++m)
#pragma unroll
        for (int nt = 0; nt < 2; ++nt) { accr[m][nt] = (f32x4)(0.f); acci[m][nt] = (f32x4)(0.f); }

    // prologue prefetch (substage 0)
    f32x4 pf[2];
    pf[0] = *(const f32x4*)(ArB + aoff);
    pf[1] = *(const f32x4*)(AiB + aoff);

#pragma unroll 2
    for (int ss = 0; ss < 8; ++ss) {
        short* bufR = &sA[ss & 1][0][0];
        short* bufI = &sA[ss & 1][1][0];

        // convert prefetched fp32 -> bf16 LDS (swizzled)
        {
            uint2 u, v;
            u.x = pack_bf16_2(pf[0][0], pf[0][1]);
            u.y = pack_bf16_2(pf[0][2], pf[0][3]);
            v.x = pack_bf16_2(pf[1][0], pf[1][1]);
            v.y = pack_bf16_2(pf[1][2], pf[1][3]);
            *(uint2*)&bufR[waddr] = u;
            *(uint2*)&bufI[waddr] = v;
        }
        __syncthreads();   // single barrier per substage (dbuf makes it sufficient)

        // issue next substage's global loads (fly during MFMA below)
        if (ss < 7) {
            const unsigned jn = (unsigned)(ss + 1) * 64;
            pf[0] = *(const f32x4*)(ArB + aoff + jn);
            pf[1] = *(const f32x4*)(AiB + aoff + jn);
        }

        const int jbase = ss * 64;
#pragma unroll
        for (int kk = 0; kk < 2; ++kk) {
            const int j = jbase + kk * 32 + quad * 8;
            short8 bkr0 = *(const short8*)(Kbr + (size_t)nn0 * 512 + j);
            short8 bkr1 = *(const short8*)(Kbr + (size_t)nn1 * 512 + j);
            short8 bki0 = *(const short8*)(Kbi + (size_t)nn0 * 512 + j);
            short8 bki1 = *(const short8*)(Kbi + (size_t)nn1 * 512 + j);
            const int rb = kk ? rb1 : rb0;

            short8 afR[2];
#pragma unroll
            for (int m = 0; m < 2; ++m)
                afR[m] = *(const short8*)&bufR[rb + m * 1024];
#pragma unroll
            for (int m = 0; m < 2; ++m) {
                accr[m][0] = __builtin_amdgcn_mfma_f32_16x16x32_bf16(afR[m], bkr0, accr[m][0], 0, 0, 0);
                accr[m][1] = __builtin_amdgcn_mfma_f32_16x16x32_bf16(afR[m], bkr1, accr[m][1], 0, 0, 0);
                acci[m][0] = __builtin_amdgcn_mfma_f32_16x16x32_bf16(afR[m], bki0, acci[m][0], 0, 0, 0);
                acci[m][1] = __builtin_amdgcn_mfma_f32_16x16x32_bf16(afR[m], bki1, acci[m][1], 0, 0, 0);
            }

            // negate ki in place (bf16 sign flip on packed pairs)
            union { short8 v; unsigned u[4]; } t0, t1;
            t0.v = bki0; t1.v = bki1;
#pragma unroll
            for (int e = 0; e < 4; ++e) { t0.u[e] ^= 0x80008000u; t1.u[e] ^= 0x80008000u; }

            short8 afI[2];
#pragma unroll
            for (int m = 0; m < 2; ++m)
                afI[m] = *(const short8*)&bufI[rb + m * 1024];
#pragma unroll
            for (int m = 0; m < 2; ++m) {
                accr[m][0] = __builtin_amdgcn_mfma_f32_16x16x32_bf16(afI[m], t0.v, accr[m][0], 0, 0, 0);
                accr[m][1] = __builtin_amdgcn_mfma_f32_16x16x32_bf16(afI[m], t1.v, accr[m][1], 0, 0, 0);
                acci[m][0] = __builtin_amdgcn_mfma_f32_16x16x32_bf16(afI[m], bkr0, acci[m][0], 0, 0, 0);
                acci[m][1] = __builtin_amdgcn_mfma_f32_16x16x32_bf16(afI[m], bkr1, acci[m][1], 0, 0, 0);
            }
        }
    }

    // ---- epilogue: i-contraction with f32 kernel, cross-quad reduce, one atomic per n
    // acc element (m,nt,r) sits at (i = i0 + m*16 + quad*4 + r, n = w*32 + nt*16 + rrow)
    float* outB = out + (size_t)b * UU;
#pragma unroll
    for (int nt = 0; nt < 2; ++nt) {
        const int n = w * 32 + nt * 16 + rrow;
        float s = 0.f;
        if (n < UU) {
            const float* kp = Kt + ((size_t)n * DD + i0 + quad * 4) * 2;  // (kr,ki) pairs
#pragma unroll
            for (int m = 0; m < 2; ++m) {
                f32x4 k01 = *(const f32x4*)(kp + m * 32);        // i+0,i+1: kr,ki,kr,ki
                f32x4 k23 = *(const f32x4*)(kp + m * 32 + 4);    // i+2,i+3
                s += accr[m][nt][0] * k01[0] - acci[m][nt][0] * k01[1];
                s += accr[m][nt][1] * k01[2] - acci[m][nt][1] * k01[3];
                s += accr[m][nt][2] * k23[0] - acci[m][nt][2] * k23[1];
                s += accr[m][nt][3] * k23[2] - acci[m][nt][3] * k23[3];
            }
        }
        s += __shfl_xor(s, 16, 64);
        s += __shfl_xor(s, 32, 64);
        if (quad == 0 && n < UU)
            atomicAdd(&outB[n], s);   // 16 i-chunk blocks per (b,n): trivial contention
    }
}

// ---- fallback (ws too small): self-contained atomic kernel, f32 Kt synthesis in LDS
#define ASTR 40
#define WSTR 40
__global__ __launch_bounds__(512, 4) void cm_gemm_fb_kernel(
    const float* __restrict__ Ar, const float* __restrict__ Ai,
    const float* __restrict__ Kt, float* __restrict__ dst)
{
    __shared__ short sAr[BB * ASTR];
    __shared__ short sAi[BB * ASTR];
    __shared__ short sWr[NP * WSTR];
    __shared__ short sWi[NP * WSTR];
    const int tid = threadIdx.x, irow = blockIdx.x;
    const int w = tid >> 6, lane = tid & 63;
    const int mw = (w & 1) * 64, nw = (w >> 1) * 64;
    const int rrow = lane & 15, quad = lane >> 4;
    const int nW = tid >> 1, jh = (tid & 1) * 16;
    float krI = 0.f, kiI = 0.f;
    if (nW < UU) { float2 s = ((const float2*)Kt)[(size_t)nW * DD + irow]; krI = s.x; kiI = s.y; }
    const int brow0 = tid >> 3, grp = tid & 7;
    const size_t aoff0 = (size_t)brow0 * DD * DD + (size_t)irow * DD + (size_t)grp * 4;
    const size_t aoff1 = aoff0 + (size_t)64 * DD * DD;
    f32x4 acc[4][4];
#pragma unroll
    for (int a = 0; a < 4; ++a)
#pragma unroll
        for (int c = 0; c < 4; ++c) acc[a][c] = (f32x4)(0.f);
    for (int jw = 0; jw < DD; jw += 32) {
        f32x4 vr0 = *(const f32x4*)(Ar + aoff0 + jw);
        f32x4 vr1 = *(const f32x4*)(Ar + aoff1 + jw);
        f32x4 vi0 = *(const f32x4*)(Ai + aoff0 + jw);
        f32x4 vi1 = *(const f32x4*)(Ai + aoff1 + jw);
        union { unsigned short s[4]; uint2 u; } t0, t1, t2, t3;
#pragma unroll
        for (int q = 0; q < 4; ++q) {
            t0.s[q] = f2bf(vr0[q]); t1.s[q] = f2bf(vr1[q]);
            t2.s[q] = f2bf(vi0[q]); t3.s[q] = f2bf(vi1[q]);
        }
        *(uint2*)&sAr[ brow0       * ASTR + grp * 4] = t0.u;
        *(uint2*)&sAr[(brow0 + 64) * ASTR + grp * 4] = t1.u;
        *(uint2*)&sAi[ brow0       * ASTR + grp * 4] = t2.u;
        *(uint2*)&sAi[(brow0 + 64) * ASTR + grp * 4] = t3.u;
        if (nW < UU) {
            const f32x4* kv = (const f32x4*)(Kt + (size_t)nW * DD * 2 + (size_t)(jw + jh) * 2);
#pragma unroll
            for (int q = 0; q < 8; ++q) {
                f32x4 v = kv[q];
                float wr0 = krI * v[0] - kiI * v[1], wi0 = -(krI * v[1] + kiI * v[0]);
                float wr1 = krI * v[2] - kiI * v[3], wi1 = -(krI * v[3] + kiI * v[2]);
                *(unsigned*)&sWr[nW * WSTR + jh + 2 * q] = (unsigned)f2bf(wr0) | ((unsigned)f2bf(wr1) << 16);
                *(unsigned*)&sWi[nW * WSTR + jh + 2 * q] = (unsigned)f2bf(wi0) | ((unsigned)f2bf(wi1) << 16);
            }
        } else {
#pragma unroll
            for (int q = 0; q < 8; ++q) {
                *(unsigned*)&sWr[nW * WSTR + jh + 2 * q] = 0u;
                *(unsigned*)&sWi[nW * WSTR + jh + 2 * q] = 0u;
            }
        }
        __syncthreads();
#pragma unroll
        for (int ph = 0; ph < 2; ++ph) {
            const short* sA = ph ? sAi : sAr;
            const short* sW = ph ? sWi : sWr;
            short8 af[4], bf[4];
#pragma unroll
            for (int t = 0; t < 4; ++t) {
                af[t] = *(const short8*)&sA[(mw + t * 16 + rrow) * ASTR + quad * 8];
                bf[t] = *(const short8*)&sW[(nw + t * 16 + rrow) * WSTR + quad * 8];
            }
#pragma unroll
            for (int ti = 0; ti < 4; ++ti)
#pragma unroll
                for (int tj = 0; tj < 4; ++tj)
                    acc[ti][tj] = __builtin_amdgcn_mfma_f32_16x16x32_bf16(af[ti], bf[tj], acc[ti][tj], 0, 0, 0);
        }
        __syncthreads();
    }
#pragma unroll
    for (int ti = 0; ti < 4; ++ti) {
        int m = mw + ti * 16 + quad * 4;
#pragma unroll
        for (int tj = 0; tj < 4; ++tj) {
            int n = nw + tj * 16 + rrow;
            if (n < UU)
#pragma unroll
                for (int r = 0; r < 4; ++r)
                    atomicAdd(&dst[(size_t)(m + r) * UU + n], acc[ti][tj][r]);
        }
    }
}

extern "C" void kernel_launch(void* const* d_in, const int* in_sizes, int n_in,
                              void* d_out, int out_size, void* d_ws, size_t ws_size,
                              hipStream_t stream) {
    const float* Ar = (const float*)d_in[0];
    const float* Ai = (const float*)d_in[1];
    const float* Kt = (const float*)d_in[2];
    float* out = (float*)d_out;

    const size_t kb_need = (size_t)2 * NP * DD * sizeof(unsigned short);  // 512 KB

    if (ws_size >= kb_need) {
        unsigned short* Kbr = (unsigned short*)d_ws;
        unsigned short* Kbi = Kbr + (size_t)NP * DD;
        hipLaunchKernelGGL(kb2_build_kernel, dim3(512), dim3(256), 0, stream, Kt, Kbr, Kbi, out);
        hipLaunchKernelGGL(qf_gemm_kernel, dim3(2048), dim3(512), 0, stream,
                           Ar, Ai, Kt, Kbr, Kbi, out);
    } else {
        hipLaunchKernelGGL(zero_out_kernel, dim3(100), dim3(256), 0, stream, out);
        hipLaunchKernelGGL(cm_gemm_fb_kernel, dim3(DD), dim3(512), 0, stream, Ar, Ai, Kt, out);
    }
}

// Round 3
// 314.738 us; speedup vs baseline: 1.2295x; 1.1306x over previous
//
#include <hip/hip_runtime.h>
#include <hip/hip_bf16.h>
#include <string.h>

#define BB 128
#define UU 200
#define DD 512
#define NP 256

typedef __attribute__((ext_vector_type(8))) short short8;
typedef __attribute__((ext_vector_type(4))) float f32x4;

__device__ __forceinline__ unsigned pack_bf16_2(float a, float b) {
    __hip_bfloat162 h = __float22bfloat162_rn(make_float2(a, b));
    unsigned u; memcpy(&u, &h, 4); return u;
}

__device__ __forceinline__ unsigned short f2bf(float x) {
    union { float f; unsigned u; } v; v.f = x;
    unsigned r = v.u + 0x7FFFu + ((v.u >> 16) & 1u);
    return (unsigned short)(r >> 16);
}

// ---- build plain bf16 tables Kbr[n][j], Kbi[n][j] (n padded to 256 with zeros).
// Also pre-zeroes out[] (25600 < 131072, same stream => done before gemm atomics).
__global__ void kb2_build_kernel(const float* __restrict__ Kt,
                                 unsigned short* __restrict__ Kbr,
                                 unsigned short* __restrict__ Kbi,
                                 float* __restrict__ out) {
    int idx = blockIdx.x * 256 + threadIdx.x;    // 0..131071 (256 n x 512 j)
    int n = idx >> 9, j = idx & 511;
    unsigned short r = 0, im = 0;
    if (n < UU) {
        float2 s = ((const float2*)Kt)[(size_t)n * DD + j];
        r = f2bf(s.x); im = f2bf(s.y);
    }
    Kbr[idx] = r;
    Kbi[idx] = im;
    if (idx < BB * UU) out[idx] = 0.0f;
}

__global__ void zero_out_kernel(float* __restrict__ out) {
    int i = blockIdx.x * 256 + threadIdx.x;
    if (i < BB * UU) out[i] = 0.0f;
}

// ---- quadratic-form GEMM, v3:
//   Mr[i,n] = sum_j Ar[b,i,j]*kr[n,j] - Ai[b,i,j]*ki[n,j]
//   Mi[i,n] = sum_j Ar[b,i,j]*ki[n,j] + Ai[b,i,j]*kr[n,j]
//   out[b,n] += sum_i kr[n,i]*Mr[i,n] - ki[n,i]*Mi[i,n]   (i-contraction in-block)
// Block = (b, 64-row i-chunk): grid 1024, 1024 threads = 16 waves; wave w owns
// n-slice [16w,16w+16) -> acc only 32 regs/thread. 2-deep A prefetch (pfA/pfB)
// keeps ~32KB/CU HBM loads in flight (latency fully hidden). Kb fragments are
// issued first each substage (L2) so their vmcnt wait excludes the HBM loads.
// M=64 halves round-2's Kb:A L2-traffic ratio to 2:1. 32KB LDS.
__global__ __launch_bounds__(1024, 4) void qf_gemm_kernel(
    const float* __restrict__ Ar, const float* __restrict__ Ai,
    const float* __restrict__ Kt,
    const unsigned short* __restrict__ Kbr, const unsigned short* __restrict__ Kbi,
    float* __restrict__ out)
{
    __shared__ short sA[2][2][64 * 64];   // [dbuf][Ar/Ai][row*64+j], XOR-swizzled, 32 KB

    const int tid  = threadIdx.x;
    const int bx   = blockIdx.x;          // 0..1023
    const int b    = bx >> 3;
    const int i0   = (bx & 7) * 64;

    const int w    = tid >> 6;            // 0..15
    const int lane = tid & 63;
    const int rrow = lane & 15;
    const int quad = lane >> 4;
    const int xr   = rrow & 7;
    const int nn   = w * 16 + rrow;       // this lane's n column (0..255)

    // staging: thread loads 1 granule (4 floats) per tensor per substage (64x64 chunk)
    const int g  = tid & 15;              // j-group (g*4 floats)
    const int r0 = tid >> 4;              // row 0..63
    const float* ArB = Ar + ((size_t)b * DD + i0) * DD;
    const float* AiB = Ai + ((size_t)b * DD + i0) * DD;
    const unsigned aoff  = (unsigned)r0 * DD + (unsigned)g * 4;
    const int      waddr = r0 * 64 + (((g >> 1) ^ (r0 & 7)) * 8) + (g & 1) * 4;

    // LDS read bases (in shorts): granule kk*4+quad, XOR-swizzled by rrow&7
    const int rb0 = rrow * 64 + ((quad ^ xr)) * 8;        // kk=0
    const int rb1 = rrow * 64 + ((quad ^ xr) ^ 4) * 8;    // kk=1

    const unsigned short* kbrp = Kbr + (size_t)nn * 512;
    const unsigned short* kbip = Kbi + (size_t)nn * 512;

    f32x4 accr[4], acci[4];
#pragma unroll
    for (int m = 0; m < 4; ++m) { accr[m] = (f32x4)(0.f); acci[m] = (f32x4)(0.f); }

    // 2-deep prefetch pipeline
    f32x4 pfA[2], pfB[2];
    pfA[0] = *(const f32x4*)(ArB + aoff);
    pfA[1] = *(const f32x4*)(AiB + aoff);
    pfB[0] = *(const f32x4*)(ArB + aoff + 64);
    pfB[1] = *(const f32x4*)(AiB + aoff + 64);

#define QF_SUBSTAGE(SS, PF)                                                     \
    {                                                                           \
        const int ss = (SS);                                                    \
        short* bufR = &sA[ss & 1][0][0];                                        \
        short* bufI = &sA[ss & 1][1][0];                                        \
        uint2 u, v;                                                             \
        u.x = pack_bf16_2(PF[0][0], PF[0][1]);                                  \
        u.y = pack_bf16_2(PF[0][2], PF[0][3]);                                  \
        v.x = pack_bf16_2(PF[1][0], PF[1][1]);                                  \
        v.y = pack_bf16_2(PF[1][2], PF[1][3]);                                  \
        *(uint2*)&bufR[waddr] = u;                                              \
        *(uint2*)&bufI[waddr] = v;                                              \
        __syncthreads();                                                        \
        /* Kb fragments for this substage: issued FIRST (L2, needed soonest) */ \
        const int jb = ss * 64 + quad * 8;                                      \
        short8 bkr0 = *(const short8*)(kbrp + jb);                              \
        short8 bki0 = *(const short8*)(kbip + jb);                              \
        short8 bkr1 = *(const short8*)(kbrp + jb + 32);                         \
        short8 bki1 = *(const short8*)(kbip + jb + 32);                         \
        /* A prefetch for ss+2: in flight across ~2 substages (HBM hidden) */   \
        if (ss < 6) {                                                           \
            const unsigned jn = aoff + (unsigned)(ss + 2) * 64;                 \
            PF[0] = *(const f32x4*)(ArB + jn);                                  \
            PF[1] = *(const f32x4*)(AiB + jn);                                  \
        }                                                                       \
        _Pragma("unroll")                                                       \
        for (int kk = 0; kk < 2; ++kk) {                                        \
            const short8 bkr = kk ? bkr1 : bkr0;                                \
            const short8 bki = kk ? bki1 : bki0;                                \
            const int rb = kk ? rb1 : rb0;                                      \
            short8 afR[4];                                                      \
            _Pragma("unroll")                                                   \
            for (int m = 0; m < 4; ++m)                                         \
                afR[m] = *(const short8*)&bufR[rb + m * 1024];                  \
            _Pragma("unroll")                                                   \
            for (int m = 0; m < 4; ++m) {                                       \
                accr[m] = __builtin_amdgcn_mfma_f32_16x16x32_bf16(afR[m], bkr, accr[m], 0, 0, 0); \
                acci[m] = __builtin_amdgcn_mfma_f32_16x16x32_bf16(afR[m], bki, acci[m], 0, 0, 0); \
            }                                                                   \
            union { short8 sv; unsigned uu[4]; } nb;                            \
            nb.sv = bki;                                                        \
            _Pragma("unroll")                                                   \
            for (int e = 0; e < 4; ++e) nb.uu[e] ^= 0x80008000u;                \
            short8 afI[4];                                                      \
            _Pragma("unroll")                                                   \
            for (int m = 0; m < 4; ++m)                                         \
                afI[m] = *(const short8*)&bufI[rb + m * 1024];                  \
            _Pragma("unroll")                                                   \
            for (int m = 0; m < 4; ++m) {                                       \
                accr[m] = __builtin_amdgcn_mfma_f32_16x16x32_bf16(afI[m], nb.sv, accr[m], 0, 0, 0); \
                acci[m] = __builtin_amdgcn_mfma_f32_16x16x32_bf16(afI[m], bkr, acci[m], 0, 0, 0);   \
            }                                                                   \
        }                                                                       \
    }

#pragma unroll
    for (int sp = 0; sp < 4; ++sp) {
        QF_SUBSTAGE(2 * sp,     pfA)
        QF_SUBSTAGE(2 * sp + 1, pfB)
    }
#undef QF_SUBSTAGE

    // ---- epilogue: i-contraction with f32 kernel, cross-quad reduce, one atomic per n
    // acc element (m,r) sits at (i = i0 + m*16 + quad*4 + r, n = w*16 + rrow)
    float* outB = out + (size_t)b * UU;
    {
        const int n = nn;
        float s = 0.f;
        if (n < UU) {
            const float* kp = Kt + ((size_t)n * DD + i0 + quad * 4) * 2;  // (kr,ki) pairs
#pragma unroll
            for (int m = 0; m < 4; ++m) {
                f32x4 k01 = *(const f32x4*)(kp + m * 32);        // i+0,i+1: kr,ki,kr,ki
                f32x4 k23 = *(const f32x4*)(kp + m * 32 + 4);    // i+2,i+3
                s += accr[m][0] * k01[0] - acci[m][0] * k01[1];
                s += accr[m][1] * k01[2] - acci[m][1] * k01[3];
                s += accr[m][2] * k23[0] - acci[m][2] * k23[1];
                s += accr[m][3] * k23[2] - acci[m][3] * k23[3];
            }
        }
        s += __shfl_xor(s, 16, 64);
        s += __shfl_xor(s, 32, 64);
        if (quad == 0 && n < UU)
            atomicAdd(&outB[n], s);   // 8 i-chunk blocks per (b,n): trivial contention
    }
}

// ---- fallback (ws too small): self-contained atomic kernel, f32 Kt synthesis in LDS
#define ASTR 40
#define WSTR 40
__global__ __launch_bounds__(512, 4) void cm_gemm_fb_kernel(
    const float* __restrict__ Ar, const float* __restrict__ Ai,
    const float* __restrict__ Kt, float* __restrict__ dst)
{
    __shared__ short sAr[BB * ASTR];
    __shared__ short sAi[BB * ASTR];
    __shared__ short sWr[NP * WSTR];
    __shared__ short sWi[NP * WSTR];
    const int tid = threadIdx.x, irow = blockIdx.x;
    const int w = tid >> 6, lane = tid & 63;
    const int mw = (w & 1) * 64, nw = (w >> 1) * 64;
    const int rrow = lane & 15, quad = lane >> 4;
    const int nW = tid >> 1, jh = (tid & 1) * 16;
    float krI = 0.f, kiI = 0.f;
    if (nW < UU) { float2 s = ((const float2*)Kt)[(size_t)nW * DD + irow]; krI = s.x; kiI = s.y; }
    const int brow0 = tid >> 3, grp = tid & 7;
    const size_t aoff0 = (size_t)brow0 * DD * DD + (size_t)irow * DD + (size_t)grp * 4;
    const size_t aoff1 = aoff0 + (size_t)64 * DD * DD;
    f32x4 acc[4][4];
#pragma unroll
    for (int a = 0; a < 4; ++a)
#pragma unroll
        for (int c = 0; c < 4; ++c) acc[a][c] = (f32x4)(0.f);
    for (int jw = 0; jw < DD; jw += 32) {
        f32x4 vr0 = *(const f32x4*)(Ar + aoff0 + jw);
        f32x4 vr1 = *(const f32x4*)(Ar + aoff1 + jw);
        f32x4 vi0 = *(const f32x4*)(Ai + aoff0 + jw);
        f32x4 vi1 = *(const f32x4*)(Ai + aoff1 + jw);
        union { unsigned short s[4]; uint2 u; } t0, t1, t2, t3;
#pragma unroll
        for (int q = 0; q < 4; ++q) {
            t0.s[q] = f2bf(vr0[q]); t1.s[q] = f2bf(vr1[q]);
            t2.s[q] = f2bf(vi0[q]); t3.s[q] = f2bf(vi1[q]);
        }
        *(uint2*)&sAr[ brow0       * ASTR + grp * 4] = t0.u;
        *(uint2*)&sAr[(brow0 + 64) * ASTR + grp * 4] = t1.u;
        *(uint2*)&sAi[ brow0       * ASTR + grp * 4] = t2.u;
        *(uint2*)&sAi[(brow0 + 64) * ASTR + grp * 4] = t3.u;
        if (nW < UU) {
            const f32x4* kv = (const f32x4*)(Kt + (size_t)nW * DD * 2 + (size_t)(jw + jh) * 2);
#pragma unroll
            for (int q = 0; q < 8; ++q) {
                f32x4 v = kv[q];
                float wr0 = krI * v[0] - kiI * v[1], wi0 = -(krI * v[1] + kiI * v[0]);
                float wr1 = krI * v[2] - kiI * v[3], wi1 = -(krI * v[3] + kiI * v[2]);
                *(unsigned*)&sWr[nW * WSTR + jh + 2 * q] = (unsigned)f2bf(wr0) | ((unsigned)f2bf(wr1) << 16);
                *(unsigned*)&sWi[nW * WSTR + jh + 2 * q] = (unsigned)f2bf(wi0) | ((unsigned)f2bf(wi1) << 16);
            }
        } else {
#pragma unroll
            for (int q = 0; q < 8; ++q) {
                *(unsigned*)&sWr[nW * WSTR + jh + 2 * q] = 0u;
                *(unsigned*)&sWi[nW * WSTR + jh + 2 * q] = 0u;
            }
        }
        __syncthreads();
#pragma unroll
        for (int ph = 0; ph < 2; ++ph) {
            const short* sA = ph ? sAi : sAr;
            const short* sW = ph ? sWi : sWr;
            short8 af[4], bf[4];
#pragma unroll
            for (int t = 0; t < 4; ++t) {
                af[t] = *(const short8*)&sA[(mw + t * 16 + rrow) * ASTR + quad * 8];
                bf[t] = *(const short8*)&sW[(nw + t * 16 + rrow) * WSTR + quad * 8];
            }
#pragma unroll
            for (int ti = 0; ti < 4; ++ti)
#pragma unroll
                for (int tj = 0; tj < 4; ++tj)
                    acc[ti][tj] = __builtin_amdgcn_mfma_f32_16x16x32_bf16(af[ti], bf[tj], acc[ti][tj], 0, 0, 0);
        }
        __syncthreads();
    }
#pragma unroll
    for (int ti = 0; ti < 4; ++ti) {
        int m = mw + ti * 16 + quad * 4;
#pragma unroll
        for (int tj = 0; tj < 4; ++tj) {
            int n = nw + tj * 16 + rrow;
            if (n < UU)
#pragma unroll
                for (int r = 0; r < 4; ++r)
                    atomicAdd(&dst[(size_t)(m + r) * UU + n], acc[ti][tj][r]);
        }
    }
}

extern "C" void kernel_launch(void* const* d_in, const int* in_sizes, int n_in,
                              void* d_out, int out_size, void* d_ws, size_t ws_size,
                              hipStream_t stream) {
    const float* Ar = (const float*)d_in[0];
    const float* Ai = (const float*)d_in[1];
    const float* Kt = (const float*)d_in[2];
    float* out = (float*)d_out;

    const size_t kb_need = (size_t)2 * NP * DD * sizeof(unsigned short);  // 512 KB

    if (ws_size >= kb_need) {
        unsigned short* Kbr = (unsigned short*)d_ws;
        unsigned short* Kbi = Kbr + (size_t)NP * DD;
        hipLaunchKernelGGL(kb2_build_kernel, dim3(512), dim3(256), 0, stream, Kt, Kbr, Kbi, out);
        hipLaunchKernelGGL(qf_gemm_kernel, dim3(1024), dim3(1024), 0, stream,
                           Ar, Ai, Kt, Kbr, Kbi, out);
    } else {
        hipLaunchKernelGGL(zero_out_kernel, dim3(100), dim3(256), 0, stream, out);
        hipLaunchKernelGGL(cm_gemm_fb_kernel, dim3(DD), dim3(512), 0, stream, Ar, Ai, Kt, out);
    }
}